// Round 2
// baseline (2195.679 us; speedup 1.0000x reference)
//
#include <hip/hip_runtime.h>
#include <hip/hip_bf16.h>

#define BQ 16
#define CH 192
#define HH 64
#define WW 64
#define HWSZ 4096
#define NPIX 65536
#define NHEADS 6
#define HDIM 32
#define NPAIR 96
#define KMAXR 48
#define HID 768

// ---------------- transpose NCHW -> NHWC (fp32) ----------------
__global__ __launch_bounds__(256) void k_transpose_in(const float* __restrict__ in,
                                                      float* __restrict__ out) {
  __shared__ float tile[32][33];
  int c0 = blockIdx.x * 32, hw0 = blockIdx.y * 32, b = blockIdx.z;
  int tx = threadIdx.x, ty = threadIdx.y;
  const float* src = in + (size_t)b * CH * HWSZ;
  #pragma unroll
  for (int j = 0; j < 32; j += 8)
    tile[ty + j][tx] = src[(size_t)(c0 + ty + j) * HWSZ + hw0 + tx];
  __syncthreads();
  float* dst = out + (size_t)b * HWSZ * CH;
  #pragma unroll
  for (int j = 0; j < 32; j += 8)
    dst[(size_t)(hw0 + ty + j) * CH + c0 + tx] = tile[tx][ty + j];
}

// ---------------- transpose NHWC -> NCHW (fp32) ----------------
__global__ __launch_bounds__(256) void k_transpose_out(const float* __restrict__ in,
                                                       float* __restrict__ out) {
  __shared__ float tile[32][33];
  int c0 = blockIdx.x * 32, hw0 = blockIdx.y * 32, b = blockIdx.z;
  int tx = threadIdx.x, ty = threadIdx.y;
  const float* src = in + (size_t)b * HWSZ * CH;
  #pragma unroll
  for (int j = 0; j < 32; j += 8)
    tile[ty + j][tx] = src[(size_t)(hw0 + ty + j) * CH + c0 + tx];
  __syncthreads();
  float* dst = out + (size_t)b * CH * HWSZ;
  #pragma unroll
  for (int j = 0; j < 32; j += 8)
    dst[(size_t)(c0 + ty + j) * HWSZ + hw0 + tx] = tile[tx][ty + j];
}

// ---------------- RoPE tables ----------------
__global__ __launch_bounds__(256) void k_rope(float* __restrict__ cosT, float* __restrict__ sinT) {
  int i = blockIdx.x * 256 + threadIdx.x;
  if (i >= HWSZ * NPAIR) return;
  int p = i % NPAIR;
  int hw = i / NPAIR;
  int h = hw / WW, w = hw % WW;
  int j = (p < KMAXR) ? p : p - KMAXR;
  float theta = powf(10000.f, -(float)j / (float)KMAXR);
  float pos = (p < KMAXR) ? (float)h : (float)w;
  float ang = pos * theta;
  cosT[i] = cosf(ang);
  sinT[i] = sinf(ang);
}

// ---------------- depthwise 3x3, NHWC ----------------
// MODE 0: out = in + (conv+bias)   (residual)
// MODE 1: out = silu(conv+bias)
// MODE 2: out += (conv+bias)       (add into existing)
template <int MODE>
__global__ __launch_bounds__(192) void k_dwconv(const float* __restrict__ in,
                                                const float* __restrict__ w,
                                                const float* __restrict__ bias,
                                                float* __restrict__ out) {
  int pix = blockIdx.x;
  int c = threadIdx.x;
  int hw = pix & (HWSZ - 1);
  int h = hw >> 6, ww = hw & 63;
  float acc = bias[c];
  #pragma unroll
  for (int dh = -1; dh <= 1; dh++) {
    int h2 = h + dh;
    if ((unsigned)h2 >= HH) continue;
    #pragma unroll
    for (int dw = -1; dw <= 1; dw++) {
      int w2 = ww + dw;
      if ((unsigned)w2 >= WW) continue;
      acc += w[c * 9 + (dh + 1) * 3 + (dw + 1)] *
             in[(size_t)(pix + dh * WW + dw) * CH + c];
    }
  }
  size_t oi = (size_t)pix * CH + c;
  if (MODE == 0) out[oi] = in[oi] + acc;
  else if (MODE == 1) out[oi] = acc / (1.f + expf(-acc));
  else out[oi] += acc;
}

// ---------------- LayerNorm over channel (192) per pixel ----------------
__global__ __launch_bounds__(256) void k_ln(const float* __restrict__ in,
                                            const float* __restrict__ g,
                                            const float* __restrict__ bt,
                                            float* __restrict__ out) {
  int lane = threadIdx.x & 63;
  int pix = blockIdx.x * 4 + (threadIdx.x >> 6);
  const float* p = in + (size_t)pix * CH;
  float v0 = p[lane], v1 = p[lane + 64], v2 = p[lane + 128];
  float s = v0 + v1 + v2;
  float ss = v0 * v0 + v1 * v1 + v2 * v2;
  #pragma unroll
  for (int m = 32; m; m >>= 1) {
    s += __shfl_xor(s, m, 64);
    ss += __shfl_xor(ss, m, 64);
  }
  float mu = s * (1.f / CH);
  float var = ss * (1.f / CH) - mu * mu;
  float inv = rsqrtf(var + 1e-5f);
  float* o = out + (size_t)pix * CH;
  o[lane] = (v0 - mu) * inv * g[lane] + bt[lane];
  o[lane + 64] = (v1 - mu) * inv * g[lane + 64] + bt[lane + 64];
  o[lane + 128] = (v2 - mu) * inv * g[lane + 128] + bt[lane + 128];
}

// ---------------- generic GEMM: C[M,N] = act(A[M,K] * W[N,K]^T + bias) (+res) ----------------
// ACT: 0 none, 1 silu, 2 elu+1, 3 gelu(exact)
template <int ACT, int MULA, int RES>
__global__ __launch_bounds__(256) void k_gemm(const float* __restrict__ A,
                                              const float* __restrict__ A2,
                                              const float* __restrict__ Wt,
                                              const float* __restrict__ bias,
                                              const float* __restrict__ Rsd,
                                              float* __restrict__ Cout,
                                              int M, int N, int K) {
  __shared__ float As[16][65];
  __shared__ float Bs[16][65];
  int t = threadIdx.x;
  int tx = t & 15, ty = t >> 4;
  int m0 = blockIdx.x * 64, n0 = blockIdx.y * 64;
  float acc[4][4] = {};
  for (int k0 = 0; k0 < K; k0 += 16) {
    #pragma unroll
    for (int i = 0; i < 4; i++) {
      int idx = t + i * 256;
      int m = idx >> 4, kk = idx & 15;
      float av = A[(size_t)(m0 + m) * K + k0 + kk];
      if (MULA) av *= A2[(size_t)(m0 + m) * K + k0 + kk];
      As[kk][m] = av;
      Bs[kk][m] = Wt[(size_t)(n0 + m) * K + k0 + kk];
    }
    __syncthreads();
    #pragma unroll
    for (int kk = 0; kk < 16; kk++) {
      float a[4], b[4];
      #pragma unroll
      for (int i = 0; i < 4; i++) a[i] = As[kk][ty * 4 + i];
      #pragma unroll
      for (int j = 0; j < 4; j++) b[j] = Bs[kk][tx * 4 + j];
      #pragma unroll
      for (int i = 0; i < 4; i++)
        #pragma unroll
        for (int j = 0; j < 4; j++) acc[i][j] += a[i] * b[j];
    }
    __syncthreads();
  }
  #pragma unroll
  for (int i = 0; i < 4; i++) {
    int m = m0 + ty * 4 + i;
    #pragma unroll
    for (int j = 0; j < 4; j++) {
      int n = n0 + tx * 4 + j;
      float v = acc[i][j] + bias[n];
      if (ACT == 1) v = v / (1.f + expf(-v));
      else if (ACT == 2) v = (v > 0.f) ? v + 1.f : expf(v);
      else if (ACT == 3) v = 0.5f * v * (1.f + erff(v * 0.70710678118654752f));
      if (RES) v += Rsd[(size_t)m * N + n];
      Cout[(size_t)m * N + n] = v;
    }
  }
}

// ---------------- kmean: mean over n of k (non-rope), per (b,head,d) ----------------
__global__ __launch_bounds__(256) void k_kmean(const float* __restrict__ k,
                                               float* __restrict__ kmean) {
  int bh = blockIdx.x;
  int b = bh / NHEADS, hd = bh % NHEADS;
  int d = threadIdx.x & 31;
  int part = threadIdx.x >> 5;  // 8 parts of 512
  float s = 0.f;
  for (int n = part * 512; n < (part + 1) * 512; n++)
    s += k[(size_t)(b * HWSZ + n) * CH + hd * HDIM + d];
  __shared__ float red[8][32];
  red[part][d] = s;
  __syncthreads();
  if (part == 0) {
    float t = 0.f;
    #pragma unroll
    for (int p = 0; p < 8; p++) t += red[p][d];
    kmean[bh * HDIM + d] = t * (1.f / 4096.f);
  }
}

// ---------------- kv = (1/4096) * sum_n k_rope[n,d] * v[n,e], per (b,h) ----------------
__global__ __launch_bounds__(256) void k_kv(const float* __restrict__ k,
                                            const float* __restrict__ v,
                                            const float* __restrict__ cosT,
                                            const float* __restrict__ sinT,
                                            float* __restrict__ kv) {
  int bh = blockIdx.x;
  int b = bh / NHEADS, hd = bh % NHEADS;
  int n0 = blockIdx.y * 128;
  __shared__ __align__(16) float ks[128][32];
  __shared__ __align__(16) float vs[128][32];
  #pragma unroll
  for (int it = 0; it < 8; it++) {
    int id = threadIdx.x + it * 256;  // 0..2047 : 128 rows x 16 pairs
    int pr = id & 15;
    int row = id >> 4;
    int n = n0 + row;
    size_t gi = (size_t)(b * HWSZ + n) * CH + hd * HDIM + pr * 2;
    float re = k[gi], im = k[gi + 1];
    int p = hd * 16 + pr;
    float cs = cosT[n * NPAIR + p], sn = sinT[n * NPAIR + p];
    ks[row][pr * 2] = re * cs - im * sn;
    ks[row][pr * 2 + 1] = re * sn + im * cs;
    vs[row][pr * 2] = v[gi];
    vs[row][pr * 2 + 1] = v[gi + 1];
  }
  __syncthreads();
  int d = threadIdx.x >> 3;
  int e0 = (threadIdx.x & 7) * 4;
  float a0 = 0, a1 = 0, a2 = 0, a3 = 0;
  for (int i = 0; i < 128; i++) {
    float kd = ks[i][d];
    float4 vv = *(const float4*)&vs[i][e0];
    a0 += kd * vv.x;
    a1 += kd * vv.y;
    a2 += kd * vv.z;
    a3 += kd * vv.w;
  }
  float* dst = kv + (size_t)bh * (HDIM * HDIM) + d * HDIM + e0;
  const float sc = 1.f / 4096.f;
  atomicAdd(dst + 0, a0 * sc);
  atomicAdd(dst + 1, a1 * sc);
  atomicAdd(dst + 2, a2 * sc);
  atomicAdd(dst + 3, a3 * sc);
}

// ---------------- attn[pix, hd*32+e] = z * sum_d q_rope[d] * kv[d][e] ----------------
__global__ __launch_bounds__(256) void k_attn(const float* __restrict__ q,
                                              const float* __restrict__ kv,
                                              const float* __restrict__ kmean,
                                              const float* __restrict__ cosT,
                                              const float* __restrict__ sinT,
                                              float* __restrict__ attn) {
  int gid = blockIdx.x * 256 + threadIdx.x;  // NPIX * 6 * 32 total
  int e = gid & 31;
  int t2 = gid >> 5;
  int hd = t2 % NHEADS;
  int pix = t2 / NHEADS;
  int hw = pix & (HWSZ - 1);
  int b = pix >> 12;
  const float* qp = q + (size_t)pix * CH + hd * HDIM;
  const float* kvp = kv + (size_t)(b * NHEADS + hd) * (HDIM * HDIM);
  const float* km = kmean + (b * NHEADS + hd) * HDIM;
  float z = 0.f, acc = 0.f;
  #pragma unroll
  for (int dp = 0; dp < 16; dp++) {
    float re = qp[2 * dp], im = qp[2 * dp + 1];
    z += re * km[2 * dp] + im * km[2 * dp + 1];
    int p = hd * 16 + dp;
    float cs = cosT[hw * NPAIR + p], sn = sinT[hw * NPAIR + p];
    float qr = re * cs - im * sn;
    float qi = re * sn + im * cs;
    acc += qr * kvp[(2 * dp) * HDIM + e] + qi * kvp[(2 * dp + 1) * HDIM + e];
  }
  attn[(size_t)pix * CH + hd * HDIM + e] = acc / (z + 1e-6f);
}

extern "C" void kernel_launch(void* const* d_in, const int* in_sizes, int n_in,
                              void* d_out, int out_size, void* d_ws, size_t ws_size,
                              hipStream_t stream) {
  const float* x = (const float*)d_in[0];
  const float* cpe1w = (const float*)d_in[1];
  const float* cpe1b = (const float*)d_in[2];
  const float* n1w = (const float*)d_in[3];
  const float* n1b = (const float*)d_in[4];
  const float* apw = (const float*)d_in[5];
  const float* apb = (const float*)d_in[6];
  const float* ipw = (const float*)d_in[7];
  const float* ipb = (const float*)d_in[8];
  const float* dwcw = (const float*)d_in[9];
  const float* dwcb = (const float*)d_in[10];
  const float* qkw = (const float*)d_in[11];
  const float* qkb = (const float*)d_in[12];
  const float* lepw = (const float*)d_in[13];
  const float* lepb = (const float*)d_in[14];
  const float* opw = (const float*)d_in[15];
  const float* opb = (const float*)d_in[16];
  const float* cpe2w = (const float*)d_in[17];
  const float* cpe2b = (const float*)d_in[18];
  const float* n2w = (const float*)d_in[19];
  const float* n2b = (const float*)d_in[20];
  const float* f1w = (const float*)d_in[21];
  const float* f1b = (const float*)d_in[22];
  const float* f2w = (const float*)d_in[23];
  const float* f2b = (const float*)d_in[24];
  float* out = (float*)d_out;

  float* ws = (float*)d_ws;
  const size_t S = (size_t)NPIX * CH;
  float* W0 = ws;            // Xn / y / t,v / X3
  float* W1 = ws + S;        // X1 / X2 / final NHWC
  float* W2 = ws + 2 * S;    // act_res / ln2 out
  float* W3 = ws + 3 * S;    // y2 / q / mlp hidden stripe
  float* W4 = ws + 4 * S;    // k / attn
  float* COS = ws + 5 * S;
  float* SIN = COS + (size_t)HWSZ * NPAIR;
  float* KV = SIN + (size_t)HWSZ * NPAIR;
  float* KM = KV + BQ * NHEADS * HDIM * HDIM;

  dim3 tb(32, 8);
  // 1. transpose input NCHW -> NHWC
  k_transpose_in<<<dim3(6, 128, BQ), tb, 0, stream>>>(x, W0);
  // 2. rope tables
  k_rope<<<dim3(HWSZ * NPAIR / 256), dim3(256), 0, stream>>>(COS, SIN);
  // 3. x1 = x + cpe1(x)
  k_dwconv<0><<<dim3(NPIX), dim3(CH), 0, stream>>>(W0, cpe1w, cpe1b, W1);
  // 4. y = LN1(x1)
  k_ln<<<dim3(NPIX / 4), dim3(256), 0, stream>>>(W1, n1w, n1b, W0);
  // 5. act_res = silu(act_proj(y))
  k_gemm<1, 0, 0><<<dim3(NPIX / 64, 3), dim3(256), 0, stream>>>(
      W0, (const float*)nullptr, apw, apb, (const float*)nullptr, W2, NPIX, CH, CH);
  // 6. y2 = in_proj(y)
  k_gemm<0, 0, 0><<<dim3(NPIX / 64, 3), dim3(256), 0, stream>>>(
      W0, (const float*)nullptr, ipw, ipb, (const float*)nullptr, W3, NPIX, CH, CH);
  // 7. t = silu(dwc(y2))  (= v)
  k_dwconv<1><<<dim3(NPIX), dim3(CH), 0, stream>>>(W3, dwcw, dwcb, W0);
  // 8. q = elu(t @ qk_w[0:192]^T + b)+1
  k_gemm<2, 0, 0><<<dim3(NPIX / 64, 3), dim3(256), 0, stream>>>(
      W0, (const float*)nullptr, qkw, qkb, (const float*)nullptr, W3, NPIX, CH, CH);
  // 9. k = elu(t @ qk_w[192:384]^T + b)+1
  k_gemm<2, 0, 0><<<dim3(NPIX / 64, 3), dim3(256), 0, stream>>>(
      W0, (const float*)nullptr, qkw + CH * CH, qkb + CH, (const float*)nullptr, W4, NPIX, CH, CH);
  // 10. kmean
  k_kmean<<<dim3(BQ * NHEADS), dim3(256), 0, stream>>>(W4, KM);
  // 11. kv accumulate
  hipMemsetAsync(KV, 0, (size_t)BQ * NHEADS * HDIM * HDIM * sizeof(float), stream);
  k_kv<<<dim3(BQ * NHEADS, 32), dim3(256), 0, stream>>>(W4, W0, COS, SIN, KV);
  // 12. attn = (q_rope @ kv) * z   -> W4 (k no longer needed)
  k_attn<<<dim3(NPIX * CH / 256), dim3(256), 0, stream>>>(W3, KV, KM, COS, SIN, W4);
  // 13. attn += lepe(v)
  k_dwconv<2><<<dim3(NPIX), dim3(CH), 0, stream>>>(W0, lepw, lepb, W4);
  // 14. x2 = x1 + out_proj(attn * act_res)
  k_gemm<0, 1, 1><<<dim3(NPIX / 64, 3), dim3(256), 0, stream>>>(
      W4, W2, opw, opb, W1, W1, NPIX, CH, CH);
  // 15. x3 = x2 + cpe2(x2)
  k_dwconv<0><<<dim3(NPIX), dim3(CH), 0, stream>>>(W1, cpe2w, cpe2b, W0);
  // 16. y4 = LN2(x3)
  k_ln<<<dim3(NPIX / 4), dim3(256), 0, stream>>>(W0, n2w, n2b, W2);
  // 17. MLP striped: hidden stripe fits in one S buffer
  for (int s = 0; s < 4; s++) {
    size_t off = (size_t)s * (NPIX / 4) * CH;
    k_gemm<3, 0, 0><<<dim3((NPIX / 4) / 64, HID / 64), dim3(256), 0, stream>>>(
        W2 + off, (const float*)nullptr, f1w, f1b, (const float*)nullptr, W3, NPIX / 4, HID, CH);
    k_gemm<0, 0, 1><<<dim3((NPIX / 4) / 64, 3), dim3(256), 0, stream>>>(
        W3, (const float*)nullptr, f2w, f2b, W0 + off, W1 + off, NPIX / 4, CH, HID);
  }
  // 18. final transpose NHWC -> NCHW
  k_transpose_out<<<dim3(6, 128, BQ), tb, 0, stream>>>(W1, out);
}

// Round 3
// 809.743 us; speedup vs baseline: 2.7116x; 2.7116x over previous
//
#include <hip/hip_runtime.h>
#include <hip/hip_bf16.h>

#define BQ 16
#define CH 192
#define HH 64
#define WW 64
#define HWSZ 4096
#define NPIX 65536
#define NHEADS 6
#define HDIM 32
#define NPAIR 96
#define KMAXR 48
#define HID 768

typedef __hip_bfloat16 bf16;
typedef __attribute__((ext_vector_type(8))) short short8;
typedef __attribute__((ext_vector_type(4))) float floatx4;

// ---------------- transpose NCHW -> NHWC (fp32) ----------------
__global__ __launch_bounds__(256) void k_transpose_in(const float* __restrict__ in,
                                                      float* __restrict__ out) {
  __shared__ float tile[32][33];
  int c0 = blockIdx.x * 32, hw0 = blockIdx.y * 32, b = blockIdx.z;
  int tx = threadIdx.x, ty = threadIdx.y;
  const float* src = in + (size_t)b * CH * HWSZ;
  #pragma unroll
  for (int j = 0; j < 32; j += 8)
    tile[ty + j][tx] = src[(size_t)(c0 + ty + j) * HWSZ + hw0 + tx];
  __syncthreads();
  float* dst = out + (size_t)b * HWSZ * CH;
  #pragma unroll
  for (int j = 0; j < 32; j += 8)
    dst[(size_t)(hw0 + ty + j) * CH + c0 + tx] = tile[tx][ty + j];
}

// ---------------- transpose NHWC -> NCHW (fp32) ----------------
__global__ __launch_bounds__(256) void k_transpose_out(const float* __restrict__ in,
                                                       float* __restrict__ out) {
  __shared__ float tile[32][33];
  int c0 = blockIdx.x * 32, hw0 = blockIdx.y * 32, b = blockIdx.z;
  int tx = threadIdx.x, ty = threadIdx.y;
  const float* src = in + (size_t)b * HWSZ * CH;
  #pragma unroll
  for (int j = 0; j < 32; j += 8)
    tile[ty + j][tx] = src[(size_t)(hw0 + ty + j) * CH + c0 + tx];
  __syncthreads();
  float* dst = out + (size_t)b * CH * HWSZ;
  #pragma unroll
  for (int j = 0; j < 32; j += 8)
    dst[(size_t)(c0 + ty + j) * HWSZ + hw0 + tx] = tile[tx][ty + j];
}

// ---------------- RoPE tables, layout [pair][hw] ----------------
__global__ __launch_bounds__(256) void k_rope(float* __restrict__ cosT, float* __restrict__ sinT) {
  int i = blockIdx.x * 256 + threadIdx.x;
  if (i >= NPAIR * HWSZ) return;
  int hw = i & (HWSZ - 1);
  int p = i >> 12;
  int h = hw >> 6, w = hw & 63;
  int j = (p < KMAXR) ? p : p - KMAXR;
  float theta = powf(10000.f, -(float)j / (float)KMAXR);
  float pos = (p < KMAXR) ? (float)h : (float)w;
  float ang = pos * theta;
  cosT[i] = cosf(ang);
  sinT[i] = sinf(ang);
}

// ---------------- depthwise 3x3, NHWC, row-sliding window ----------------
// MODE 0: out = in + (conv+bias)   MODE 1: out = silu(conv+bias)   MODE 2: out += (conv+bias)
template <int MODE>
__global__ __launch_bounds__(192) void k_dwconv(const float* __restrict__ in,
                                                const float* __restrict__ w,
                                                const float* __restrict__ bias,
                                                float* __restrict__ out) {
  int bh = blockIdx.x;  // b*64 + h
  int b = bh >> 6, h = bh & 63;
  int c = threadIdx.x;
  float wg[9];
  #pragma unroll
  for (int i = 0; i < 9; i++) wg[i] = w[c * 9 + i];
  float bs = bias[c];
  const size_t rowS = (size_t)WW * CH;
  const float* base = in + ((size_t)b * HWSZ + (size_t)h * WW) * CH + c;
  float* obase = out + ((size_t)b * HWSZ + (size_t)h * WW) * CH + c;
  bool hT = h > 0, hB = h < HH - 1;
  float t0 = 0, t1, t2, m0 = 0, m1, m2, b0 = 0, b1, b2;
  t1 = hT ? base[-(long)rowS] : 0.f;
  t2 = hT ? base[-(long)rowS + CH] : 0.f;
  m1 = base[0];
  m2 = base[CH];
  b1 = hB ? base[rowS] : 0.f;
  b2 = hB ? base[rowS + CH] : 0.f;
  for (int ww = 0; ww < WW; ww++) {
    float acc = bs + t0 * wg[0] + t1 * wg[1] + t2 * wg[2] + m0 * wg[3] + m1 * wg[4] +
                m2 * wg[5] + b0 * wg[6] + b1 * wg[7] + b2 * wg[8];
    float ctr = m1;
    size_t oi = (size_t)ww * CH;
    if (MODE == 0) obase[oi] = ctr + acc;
    else if (MODE == 1) obase[oi] = acc / (1.f + expf(-acc));
    else obase[oi] += acc;
    t0 = t1; t1 = t2; m0 = m1; m1 = m2; b0 = b1; b1 = b2;
    if (ww < WW - 2) {
      const float* nx = base + (size_t)(ww + 2) * CH;
      t2 = hT ? nx[-(long)rowS] : 0.f;
      m2 = nx[0];
      b2 = hB ? nx[rowS] : 0.f;
    } else { t2 = 0.f; m2 = 0.f; b2 = 0.f; }
  }
}

// ---------------- LayerNorm over channel (192) per pixel ----------------
__global__ __launch_bounds__(256) void k_ln(const float* __restrict__ in,
                                            const float* __restrict__ g,
                                            const float* __restrict__ bt,
                                            float* __restrict__ out) {
  int lane = threadIdx.x & 63;
  int pix = blockIdx.x * 4 + (threadIdx.x >> 6);
  const float* p = in + (size_t)pix * CH;
  float v0 = p[lane], v1 = p[lane + 64], v2 = p[lane + 128];
  float s = v0 + v1 + v2;
  float ss = v0 * v0 + v1 * v1 + v2 * v2;
  #pragma unroll
  for (int m = 32; m; m >>= 1) {
    s += __shfl_xor(s, m, 64);
    ss += __shfl_xor(ss, m, 64);
  }
  float mu = s * (1.f / CH);
  float var = ss * (1.f / CH) - mu * mu;
  float inv = rsqrtf(var + 1e-5f);
  float* o = out + (size_t)pix * CH;
  o[lane] = (v0 - mu) * inv * g[lane] + bt[lane];
  o[lane + 64] = (v1 - mu) * inv * g[lane + 64] + bt[lane + 64];
  o[lane + 128] = (v2 - mu) * inv * g[lane + 128] + bt[lane + 128];
}

// ---------------- MFMA bf16 GEMM: C[M,N] = act(A[M,K] @ Wt[N,K]^T + bias) (+res) ----------
// tile 128(M) x 64(N), BK=32, 4 waves: wave w computes rows [w*32, w*32+32)
// ACT: 0 none, 1 silu, 2 elu+1, 3 gelu(exact)
template <int ACT, int MULA, int RES>
__global__ __launch_bounds__(256) void k_gemm(const float* __restrict__ A,
                                              const float* __restrict__ A2,
                                              const float* __restrict__ Wt,
                                              const float* __restrict__ bias,
                                              const float* __restrict__ Rsd,
                                              float* __restrict__ Cout,
                                              int M, int N, int K) {
  __shared__ bf16 As[128][40];  // row stride 80B (16B-aligned, 2-way-conflict free)
  __shared__ bf16 Bs[64][40];
  int t = threadIdx.x;
  int wave = t >> 6, lane = t & 63;
  int quad = lane >> 4, l16 = lane & 15;
  int m0 = blockIdx.x * 128, n0 = blockIdx.y * 64;
  floatx4 acc[2][4] = {};
  for (int k0 = 0; k0 < K; k0 += 32) {
    // stage A: 128x32 fp32 -> bf16
    #pragma unroll
    for (int i = 0; i < 4; i++) {
      int idx = t + i * 256;       // one float4 each
      int m = idx >> 3;
      int kk = (idx & 7) * 4;
      float4 v = *(const float4*)&A[(size_t)(m0 + m) * K + k0 + kk];
      if (MULA) {
        float4 u = *(const float4*)&A2[(size_t)(m0 + m) * K + k0 + kk];
        v.x *= u.x; v.y *= u.y; v.z *= u.z; v.w *= u.w;
      }
      __align__(8) bf16 tmp[4] = {__float2bfloat16(v.x), __float2bfloat16(v.y),
                                  __float2bfloat16(v.z), __float2bfloat16(v.w)};
      *(uint2*)&As[m][kk] = *(uint2*)tmp;
    }
    // stage B: 64x32 fp32 -> bf16
    #pragma unroll
    for (int i = 0; i < 2; i++) {
      int idx = t + i * 256;
      int n = idx >> 3;
      int kk = (idx & 7) * 4;
      float4 v = *(const float4*)&Wt[(size_t)(n0 + n) * K + k0 + kk];
      __align__(8) bf16 tmp[4] = {__float2bfloat16(v.x), __float2bfloat16(v.y),
                                  __float2bfloat16(v.z), __float2bfloat16(v.w)};
      *(uint2*)&Bs[n][kk] = *(uint2*)tmp;
    }
    __syncthreads();
    short8 af[2], bfr[4];
    #pragma unroll
    for (int i = 0; i < 2; i++)
      af[i] = *(const short8*)&As[wave * 32 + i * 16 + l16][quad * 8];
    #pragma unroll
    for (int j = 0; j < 4; j++)
      bfr[j] = *(const short8*)&Bs[j * 16 + l16][quad * 8];
    #pragma unroll
    for (int i = 0; i < 2; i++)
      #pragma unroll
      for (int j = 0; j < 4; j++)
        acc[i][j] = __builtin_amdgcn_mfma_f32_16x16x32_bf16(af[i], bfr[j], acc[i][j], 0, 0, 0);
    __syncthreads();
  }
  // epilogue: D row = quad*4 + r, col = l16
  #pragma unroll
  for (int i = 0; i < 2; i++) {
    #pragma unroll
    for (int j = 0; j < 4; j++) {
      int n = n0 + j * 16 + l16;
      float bn = bias[n];
      #pragma unroll
      for (int r = 0; r < 4; r++) {
        int m = m0 + wave * 32 + i * 16 + quad * 4 + r;
        float v = acc[i][j][r] + bn;
        if (ACT == 1) v = v / (1.f + expf(-v));
        else if (ACT == 2) v = (v > 0.f) ? v + 1.f : expf(v);
        else if (ACT == 3) v = 0.5f * v * (1.f + erff(v * 0.70710678118654752f));
        if (RES) v += Rsd[(size_t)m * N + n];
        Cout[(size_t)m * N + n] = v;
      }
    }
  }
}

// ---------------- kmean ----------------
__global__ __launch_bounds__(256) void k_kmean(const float* __restrict__ k,
                                               float* __restrict__ kmean) {
  int bh = blockIdx.x;
  int b = bh / NHEADS, hd = bh % NHEADS;
  int d = threadIdx.x & 31;
  int part = threadIdx.x >> 5;
  float s = 0.f;
  for (int n = part * 512; n < (part + 1) * 512; n++)
    s += k[(size_t)(b * HWSZ + n) * CH + hd * HDIM + d];
  __shared__ float red[8][32];
  red[part][d] = s;
  __syncthreads();
  if (part == 0) {
    float t = 0.f;
    #pragma unroll
    for (int p = 0; p < 8; p++) t += red[p][d];
    kmean[bh * HDIM + d] = t * (1.f / 4096.f);
  }
}

// ---------------- kv = (1/4096) * sum_n rope(k)[n,d] * v[n,e], per (b,h) ----------------
__global__ __launch_bounds__(256) void k_kv(const float* __restrict__ k,
                                            const float* __restrict__ v,
                                            const float* __restrict__ cosT,
                                            const float* __restrict__ sinT,
                                            float* __restrict__ kv) {
  int bh = blockIdx.x;
  int b = bh / NHEADS, hd = bh % NHEADS;
  int n0 = blockIdx.y * 128;
  __shared__ __align__(16) float ks[128][32];
  __shared__ __align__(16) float vs[128][32];
  __shared__ float csL[16][130], snL[16][130];
  int t = threadIdx.x;
  #pragma unroll
  for (int it = 0; it < 8; it++) {
    int id = t + it * 256;
    int row = id & 127, pr = id >> 7;
    csL[pr][row] = cosT[(size_t)(hd * 16 + pr) * HWSZ + n0 + row];
    snL[pr][row] = sinT[(size_t)(hd * 16 + pr) * HWSZ + n0 + row];
  }
  __syncthreads();
  #pragma unroll
  for (int it = 0; it < 8; it++) {
    int id = t + it * 256;
    int pr = id & 15, row = id >> 4;
    int n = n0 + row;
    size_t gi = (size_t)(b * HWSZ + n) * CH + hd * HDIM + pr * 2;
    float re = k[gi], im = k[gi + 1];
    float cs = csL[pr][row], sn = snL[pr][row];
    ks[row][pr * 2] = re * cs - im * sn;
    ks[row][pr * 2 + 1] = re * sn + im * cs;
    vs[row][pr * 2] = v[gi];
    vs[row][pr * 2 + 1] = v[gi + 1];
  }
  __syncthreads();
  int d = t >> 3;
  int e0 = (t & 7) * 4;
  float a0 = 0, a1 = 0, a2 = 0, a3 = 0;
  for (int i = 0; i < 128; i++) {
    float kd = ks[i][d];
    float4 vv = *(const float4*)&vs[i][e0];
    a0 += kd * vv.x;
    a1 += kd * vv.y;
    a2 += kd * vv.z;
    a3 += kd * vv.w;
  }
  float* dst = kv + (size_t)bh * (HDIM * HDIM) + d * HDIM + e0;
  const float sc = 1.f / 4096.f;
  atomicAdd(dst + 0, a0 * sc);
  atomicAdd(dst + 1, a1 * sc);
  atomicAdd(dst + 2, a2 * sc);
  atomicAdd(dst + 3, a3 * sc);
}

// ---------------- attn: per (pix-chunk, head, batch); kv in LDS ----------------
__global__ __launch_bounds__(256) void k_attn(const float* __restrict__ q,
                                              const float* __restrict__ kv,
                                              const float* __restrict__ kmean,
                                              const float* __restrict__ cosT,
                                              const float* __restrict__ sinT,
                                              float* __restrict__ attn) {
  int hd = blockIdx.y, b = blockIdx.z;
  int hw = blockIdx.x * 256 + threadIdx.x;
  int bh = b * NHEADS + hd;
  __shared__ float kvs[32][33];
  __shared__ float kms[32];
  #pragma unroll
  for (int i = 0; i < 4; i++) {
    int idx = threadIdx.x + i * 256;
    kvs[idx >> 5][idx & 31] = kv[(size_t)bh * 1024 + idx];
  }
  if (threadIdx.x < 32) kms[threadIdx.x] = kmean[bh * HDIM + threadIdx.x];
  __syncthreads();
  int pix = b * HWSZ + hw;
  const float* qp = q + (size_t)pix * CH + hd * HDIM;
  float qv[32];
  #pragma unroll
  for (int i = 0; i < 8; i++) *(float4*)&qv[i * 4] = *(const float4*)&qp[i * 4];
  float z = 1e-6f;
  #pragma unroll
  for (int d = 0; d < 32; d++) z += qv[d] * kms[d];
  float o[32] = {};
  #pragma unroll
  for (int p = 0; p < 16; p++) {
    float cs = cosT[(size_t)(hd * 16 + p) * HWSZ + hw];
    float sn = sinT[(size_t)(hd * 16 + p) * HWSZ + hw];
    float re = qv[2 * p], im = qv[2 * p + 1];
    float qr = re * cs - im * sn;
    float qi = re * sn + im * cs;
    #pragma unroll
    for (int e = 0; e < 32; e++)
      o[e] += qr * kvs[2 * p][e] + qi * kvs[2 * p + 1][e];
  }
  float zi = 1.f / z;
  float* op = attn + (size_t)pix * CH + hd * HDIM;
  #pragma unroll
  for (int i = 0; i < 8; i++) {
    float4 v = {o[i * 4] * zi, o[i * 4 + 1] * zi, o[i * 4 + 2] * zi, o[i * 4 + 3] * zi};
    *(float4*)&op[i * 4] = v;
  }
}

extern "C" void kernel_launch(void* const* d_in, const int* in_sizes, int n_in,
                              void* d_out, int out_size, void* d_ws, size_t ws_size,
                              hipStream_t stream) {
  const float* x = (const float*)d_in[0];
  const float* cpe1w = (const float*)d_in[1];
  const float* cpe1b = (const float*)d_in[2];
  const float* n1w = (const float*)d_in[3];
  const float* n1b = (const float*)d_in[4];
  const float* apw = (const float*)d_in[5];
  const float* apb = (const float*)d_in[6];
  const float* ipw = (const float*)d_in[7];
  const float* ipb = (const float*)d_in[8];
  const float* dwcw = (const float*)d_in[9];
  const float* dwcb = (const float*)d_in[10];
  const float* qkw = (const float*)d_in[11];
  const float* qkb = (const float*)d_in[12];
  const float* lepw = (const float*)d_in[13];
  const float* lepb = (const float*)d_in[14];
  const float* opw = (const float*)d_in[15];
  const float* opb = (const float*)d_in[16];
  const float* cpe2w = (const float*)d_in[17];
  const float* cpe2b = (const float*)d_in[18];
  const float* n2w = (const float*)d_in[19];
  const float* n2b = (const float*)d_in[20];
  const float* f1w = (const float*)d_in[21];
  const float* f1b = (const float*)d_in[22];
  const float* f2w = (const float*)d_in[23];
  const float* f2b = (const float*)d_in[24];
  float* out = (float*)d_out;

  float* ws = (float*)d_ws;
  const size_t S = (size_t)NPIX * CH;
  float* W0 = ws;            // Xn / y / t,v / X3
  float* W1 = ws + S;        // X1 / X2 / final NHWC
  float* W2 = ws + 2 * S;    // act_res / ln2 out
  float* W3 = ws + 3 * S;    // y2 / q ; W3..W4 = MLP hidden (2S)
  float* W4 = ws + 4 * S;    // k / attn
  float* COS = ws + 5 * S;
  float* SIN = COS + (size_t)NPAIR * HWSZ;
  float* KV = SIN + (size_t)NPAIR * HWSZ;
  float* KM = KV + BQ * NHEADS * HDIM * HDIM;

  dim3 tb(32, 8);
  // 1. transpose input NCHW -> NHWC
  k_transpose_in<<<dim3(6, 128, BQ), tb, 0, stream>>>(x, W0);
  // 2. rope tables [pair][hw]
  k_rope<<<dim3(NPAIR * HWSZ / 256), dim3(256), 0, stream>>>(COS, SIN);
  // 3. x1 = x + cpe1(x)
  k_dwconv<0><<<dim3(BQ * HH), dim3(CH), 0, stream>>>(W0, cpe1w, cpe1b, W1);
  // 4. y = LN1(x1)
  k_ln<<<dim3(NPIX / 4), dim3(256), 0, stream>>>(W1, n1w, n1b, W0);
  // 5. act_res = silu(act_proj(y))
  k_gemm<1, 0, 0><<<dim3(NPIX / 128, 3), dim3(256), 0, stream>>>(
      W0, (const float*)nullptr, apw, apb, (const float*)nullptr, W2, NPIX, CH, CH);
  // 6. y2 = in_proj(y)
  k_gemm<0, 0, 0><<<dim3(NPIX / 128, 3), dim3(256), 0, stream>>>(
      W0, (const float*)nullptr, ipw, ipb, (const float*)nullptr, W3, NPIX, CH, CH);
  // 7. t = silu(dwc(y2))  (= v)
  k_dwconv<1><<<dim3(BQ * HH), dim3(CH), 0, stream>>>(W3, dwcw, dwcb, W0);
  // 8. q = elu(t @ qk_w[0:192]^T + b)+1
  k_gemm<2, 0, 0><<<dim3(NPIX / 128, 3), dim3(256), 0, stream>>>(
      W0, (const float*)nullptr, qkw, qkb, (const float*)nullptr, W3, NPIX, CH, CH);
  // 9. k = elu(t @ qk_w[192:384]^T + b)+1
  k_gemm<2, 0, 0><<<dim3(NPIX / 128, 3), dim3(256), 0, stream>>>(
      W0, (const float*)nullptr, qkw + CH * CH, qkb + CH, (const float*)nullptr, W4, NPIX, CH, CH);
  // 10. kmean
  k_kmean<<<dim3(BQ * NHEADS), dim3(256), 0, stream>>>(W4, KM);
  // 11. kv accumulate
  hipMemsetAsync(KV, 0, (size_t)BQ * NHEADS * HDIM * HDIM * sizeof(float), stream);
  k_kv<<<dim3(BQ * NHEADS, 32), dim3(256), 0, stream>>>(W4, W0, COS, SIN, KV);
  // 12. attn = (q_rope @ kv) * z -> W4
  k_attn<<<dim3(HWSZ / 256, NHEADS, BQ), dim3(256), 0, stream>>>(W3, KV, KM, COS, SIN, W4);
  // 13. attn += lepe(v)
  k_dwconv<2><<<dim3(BQ * HH), dim3(CH), 0, stream>>>(W0, lepw, lepb, W4);
  // 14. x2 = x1 + out_proj(attn * act_res)
  k_gemm<0, 1, 1><<<dim3(NPIX / 128, 3), dim3(256), 0, stream>>>(
      W4, W2, opw, opb, W1, W1, NPIX, CH, CH);
  // 15. x3 = x2 + cpe2(x2)
  k_dwconv<0><<<dim3(BQ * HH), dim3(CH), 0, stream>>>(W1, cpe2w, cpe2b, W0);
  // 16. y4 = LN2(x3)
  k_ln<<<dim3(NPIX / 4), dim3(256), 0, stream>>>(W0, n2w, n2b, W2);
  // 17. MLP in 2 stripes; hidden (NPIX/2 x 768 fp32 = 2S) lives in W3..W4
  for (int s = 0; s < 2; s++) {
    size_t off = (size_t)s * (NPIX / 2) * CH;
    k_gemm<3, 0, 0><<<dim3((NPIX / 2) / 128, HID / 64), dim3(256), 0, stream>>>(
        W2 + off, (const float*)nullptr, f1w, f1b, (const float*)nullptr, W3, NPIX / 2, HID, CH);
    k_gemm<0, 0, 1><<<dim3((NPIX / 2) / 128, 3), dim3(256), 0, stream>>>(
        W3, (const float*)nullptr, f2w, f2b, W0 + off, W1 + off, NPIX / 2, CH, HID);
  }
  // 18. final transpose NHWC -> NCHW
  k_transpose_out<<<dim3(6, 128, BQ), tb, 0, stream>>>(W1, out);
}

// Round 4
// 797.486 us; speedup vs baseline: 2.7533x; 1.0154x over previous
//
#include <hip/hip_runtime.h>
#include <hip/hip_bf16.h>

#define BQ 16
#define CH 192
#define HH 64
#define WW 64
#define HWSZ 4096
#define NPIX 65536
#define NHEADS 6
#define HDIM 32
#define NPAIR 96
#define KMAXR 48
#define HID 768

typedef __hip_bfloat16 bf16;
typedef __attribute__((ext_vector_type(8))) short short8;
typedef __attribute__((ext_vector_type(4))) float floatx4;

static __device__ __forceinline__ float b2f(bf16 v) { return __bfloat162float(v); }
static __device__ __forceinline__ bf16 f2b(float v) { return __float2bfloat16(v); }
static __device__ __forceinline__ float cvt(float v) { return v; }
static __device__ __forceinline__ float cvt(bf16 v) { return __bfloat162float(v); }
static __device__ __forceinline__ void stv(float* p, float v) { *p = v; }
static __device__ __forceinline__ void stv(bf16* p, float v) { *p = __float2bfloat16(v); }

template <int ACT>
static __device__ __forceinline__ float actf(float v) {
  if (ACT == 1) return v / (1.f + expf(-v));                          // silu
  if (ACT == 2) return (v > 0.f) ? v + 1.f : expf(v);                 // elu+1
  if (ACT == 3) return 0.5f * v * (1.f + erff(v * 0.70710678118654752f));  // gelu
  return v;
}

// ---------------- transpose NCHW -> NHWC (fp32) ----------------
__global__ __launch_bounds__(256) void k_transpose_in(const float* __restrict__ in,
                                                      float* __restrict__ out) {
  __shared__ float tile[32][33];
  int c0 = blockIdx.x * 32, hw0 = blockIdx.y * 32, b = blockIdx.z;
  int tx = threadIdx.x, ty = threadIdx.y;
  const float* src = in + (size_t)b * CH * HWSZ;
  #pragma unroll
  for (int j = 0; j < 32; j += 8)
    tile[ty + j][tx] = src[(size_t)(c0 + ty + j) * HWSZ + hw0 + tx];
  __syncthreads();
  float* dst = out + (size_t)b * HWSZ * CH;
  #pragma unroll
  for (int j = 0; j < 32; j += 8)
    dst[(size_t)(hw0 + ty + j) * CH + c0 + tx] = tile[tx][ty + j];
}

// ---------------- transpose NHWC -> NCHW (fp32) ----------------
__global__ __launch_bounds__(256) void k_transpose_out(const float* __restrict__ in,
                                                       float* __restrict__ out) {
  __shared__ float tile[32][33];
  int c0 = blockIdx.x * 32, hw0 = blockIdx.y * 32, b = blockIdx.z;
  int tx = threadIdx.x, ty = threadIdx.y;
  const float* src = in + (size_t)b * HWSZ * CH;
  #pragma unroll
  for (int j = 0; j < 32; j += 8)
    tile[ty + j][tx] = src[(size_t)(hw0 + ty + j) * CH + c0 + tx];
  __syncthreads();
  float* dst = out + (size_t)b * CH * HWSZ;
  #pragma unroll
  for (int j = 0; j < 32; j += 8)
    dst[(size_t)(c0 + ty + j) * HWSZ + hw0 + tx] = tile[tx][ty + j];
}

// ---------------- RoPE tables, layout [pair][hw] ----------------
__global__ __launch_bounds__(256) void k_rope(float* __restrict__ cosT, float* __restrict__ sinT) {
  int i = blockIdx.x * 256 + threadIdx.x;
  if (i >= NPAIR * HWSZ) return;
  int hw = i & (HWSZ - 1);
  int p = i >> 12;
  int h = hw >> 6, w = hw & 63;
  int j = (p < KMAXR) ? p : p - KMAXR;
  float theta = powf(10000.f, -(float)j / (float)KMAXR);
  float pos = (p < KMAXR) ? (float)h : (float)w;
  float ang = pos * theta;
  cosT[i] = cosf(ang);
  sinT[i] = sinf(ang);
}

// ---------------- depthwise 3x3, NHWC, row-sliding window ----------------
// MODE 0: out = in + conv   MODE 1: out = silu(conv)   MODE 2: out += conv
template <typename TI, typename TO, int MODE>
__global__ __launch_bounds__(192) void k_dwconv(const TI* __restrict__ in,
                                                const float* __restrict__ w,
                                                const float* __restrict__ bias,
                                                TO* __restrict__ out) {
  int bh = blockIdx.x;  // b*64 + h
  int b = bh >> 6, h = bh & 63;
  int c = threadIdx.x;
  float wg[9];
  #pragma unroll
  for (int i = 0; i < 9; i++) wg[i] = w[c * 9 + i];
  float bs = bias[c];
  const size_t rowS = (size_t)WW * CH;
  const TI* base = in + ((size_t)b * HWSZ + (size_t)h * WW) * CH + c;
  TO* obase = out + ((size_t)b * HWSZ + (size_t)h * WW) * CH + c;
  bool hT = h > 0, hB = h < HH - 1;
  float t0 = 0, t1, t2, m0 = 0, m1, m2, b0 = 0, b1, b2;
  t1 = hT ? cvt(base[-(long)rowS]) : 0.f;
  t2 = hT ? cvt(base[-(long)rowS + CH]) : 0.f;
  m1 = cvt(base[0]);
  m2 = cvt(base[CH]);
  b1 = hB ? cvt(base[rowS]) : 0.f;
  b2 = hB ? cvt(base[rowS + CH]) : 0.f;
  for (int ww = 0; ww < WW; ww++) {
    float acc = bs + t0 * wg[0] + t1 * wg[1] + t2 * wg[2] + m0 * wg[3] + m1 * wg[4] +
                m2 * wg[5] + b0 * wg[6] + b1 * wg[7] + b2 * wg[8];
    float ctr = m1;
    size_t oi = (size_t)ww * CH;
    if (MODE == 0) stv(&obase[oi], ctr + acc);
    else if (MODE == 1) stv(&obase[oi], acc / (1.f + expf(-acc)));
    else stv(&obase[oi], cvt(obase[oi]) + acc);
    t0 = t1; t1 = t2; m0 = m1; m1 = m2; b0 = b1; b1 = b2;
    if (ww < WW - 2) {
      const TI* nx = base + (size_t)(ww + 2) * CH;
      t2 = hT ? cvt(nx[-(long)rowS]) : 0.f;
      m2 = cvt(nx[0]);
      b2 = hB ? cvt(nx[rowS]) : 0.f;
    } else { t2 = 0.f; m2 = 0.f; b2 = 0.f; }
  }
}

// ---------------- LayerNorm over channel (192): fp32 in -> bf16 out ----------------
__global__ __launch_bounds__(256) void k_ln(const float* __restrict__ in,
                                            const float* __restrict__ g,
                                            const float* __restrict__ bt,
                                            bf16* __restrict__ out) {
  int lane = threadIdx.x & 63;
  int pix = blockIdx.x * 4 + (threadIdx.x >> 6);
  const float* p = in + (size_t)pix * CH;
  float v0 = p[lane], v1 = p[lane + 64], v2 = p[lane + 128];
  float s = v0 + v1 + v2;
  float ss = v0 * v0 + v1 * v1 + v2 * v2;
  #pragma unroll
  for (int m = 32; m; m >>= 1) {
    s += __shfl_xor(s, m, 64);
    ss += __shfl_xor(ss, m, 64);
  }
  float mu = s * (1.f / CH);
  float var = ss * (1.f / CH) - mu * mu;
  float inv = rsqrtf(var + 1e-5f);
  bf16* o = out + (size_t)pix * CH;
  o[lane] = f2b((v0 - mu) * inv * g[lane] + bt[lane]);
  o[lane + 64] = f2b((v1 - mu) * inv * g[lane + 64] + bt[lane + 64]);
  o[lane + 128] = f2b((v2 - mu) * inv * g[lane + 128] + bt[lane + 128]);
}

// ---------------- MFMA bf16 GEMM core macros ----------------
// tile 128(M) x 64(N), BK=32, 4 waves (wave w -> rows w*32..w*32+31)

// single-output GEMM: Cout = act(A @ Wt^T + bias) [* nothing] (+Rsd fp32)
template <int ACT, int MULA, int RES, typename TO>
__global__ __launch_bounds__(256) void k_gemm(const bf16* __restrict__ A,
                                              const bf16* __restrict__ A2,
                                              const float* __restrict__ Wt,
                                              const float* __restrict__ bias,
                                              const float* __restrict__ Rsd,
                                              TO* __restrict__ Cout,
                                              int M, int N, int K) {
  __shared__ bf16 As[128][40];
  __shared__ bf16 Bs[64][40];
  int t = threadIdx.x;
  int wave = t >> 6, lane = t & 63;
  int quad = lane >> 4, l16 = lane & 15;
  int m0 = blockIdx.x * 128, n0 = blockIdx.y * 64;
  floatx4 acc[2][4] = {};
  for (int k0 = 0; k0 < K; k0 += 32) {
    #pragma unroll
    for (int i = 0; i < 2; i++) {
      int idx = t + i * 256;
      int m = idx >> 2, kk = (idx & 3) * 8;
      const bf16* pa = &A[(size_t)(m0 + m) * K + k0 + kk];
      if (!MULA) {
        *(short8*)&As[m][kk] = *(const short8*)pa;
      } else {
        const bf16* pb = &A2[(size_t)(m0 + m) * K + k0 + kk];
        __align__(16) bf16 tmp[8];
        #pragma unroll
        for (int j = 0; j < 8; j++) tmp[j] = f2b(b2f(pa[j]) * b2f(pb[j]));
        *(short8*)&As[m][kk] = *(const short8*)tmp;
      }
    }
    #pragma unroll
    for (int i = 0; i < 2; i++) {
      int idx = t + i * 256;
      int n = idx >> 3, kk = (idx & 7) * 4;
      float4 v = *(const float4*)&Wt[(size_t)(n0 + n) * K + k0 + kk];
      __align__(8) bf16 tmp[4] = {f2b(v.x), f2b(v.y), f2b(v.z), f2b(v.w)};
      *(uint2*)&Bs[n][kk] = *(uint2*)tmp;
    }
    __syncthreads();
    short8 af[2], bfr[4];
    #pragma unroll
    for (int i = 0; i < 2; i++)
      af[i] = *(const short8*)&As[wave * 32 + i * 16 + l16][quad * 8];
    #pragma unroll
    for (int j = 0; j < 4; j++)
      bfr[j] = *(const short8*)&Bs[j * 16 + l16][quad * 8];
    #pragma unroll
    for (int i = 0; i < 2; i++)
      #pragma unroll
      for (int j = 0; j < 4; j++)
        acc[i][j] = __builtin_amdgcn_mfma_f32_16x16x32_bf16(af[i], bfr[j], acc[i][j], 0, 0, 0);
    __syncthreads();
  }
  #pragma unroll
  for (int i = 0; i < 2; i++) {
    #pragma unroll
    for (int j = 0; j < 4; j++) {
      int n = n0 + j * 16 + l16;
      float bn = bias[n];
      #pragma unroll
      for (int r = 0; r < 4; r++) {
        int m = m0 + wave * 32 + i * 16 + quad * 4 + r;
        float v = actf<ACT>(acc[i][j][r] + bn);
        if (RES) v += Rsd[(size_t)m * N + n];
        stv(&Cout[(size_t)m * N + n], v);
      }
    }
  }
}

// dual-output GEMM: N=384 split into two 192 halves with separate weights/bias/act/out.
// KMEAN: accumulate column means of half-B output (pre-bf16) into KM[b*CH+col].
template <int ACTA, int ACTB, int KMEAN>
__global__ __launch_bounds__(256) void k_gemm_dual(const bf16* __restrict__ A,
                                                   const float* __restrict__ WtA,
                                                   const float* __restrict__ biasA,
                                                   const float* __restrict__ WtB,
                                                   const float* __restrict__ biasB,
                                                   bf16* __restrict__ OutA,
                                                   bf16* __restrict__ OutB,
                                                   float* __restrict__ KM,
                                                   int K) {
  __shared__ bf16 As[128][40];
  __shared__ bf16 Bs[64][40];
  __shared__ float colsum[64];
  int t = threadIdx.x;
  int wave = t >> 6, lane = t & 63;
  int quad = lane >> 4, l16 = lane & 15;
  int m0 = blockIdx.x * 128, n0 = blockIdx.y * 64;
  int half = n0 >= 192;
  int n0l = half ? n0 - 192 : n0;
  const float* Wt = half ? WtB : WtA;
  const float* bias = half ? biasB : biasA;
  bf16* Out = half ? OutB : OutA;
  if (KMEAN && half && t < 64) colsum[t] = 0.f;
  floatx4 acc[2][4] = {};
  for (int k0 = 0; k0 < K; k0 += 32) {
    #pragma unroll
    for (int i = 0; i < 2; i++) {
      int idx = t + i * 256;
      int m = idx >> 2, kk = (idx & 3) * 8;
      *(short8*)&As[m][kk] = *(const short8*)&A[(size_t)(m0 + m) * K + k0 + kk];
    }
    #pragma unroll
    for (int i = 0; i < 2; i++) {
      int idx = t + i * 256;
      int n = idx >> 3, kk = (idx & 7) * 4;
      float4 v = *(const float4*)&Wt[(size_t)(n0l + n) * K + k0 + kk];
      __align__(8) bf16 tmp[4] = {f2b(v.x), f2b(v.y), f2b(v.z), f2b(v.w)};
      *(uint2*)&Bs[n][kk] = *(uint2*)tmp;
    }
    __syncthreads();
    short8 af[2], bfr[4];
    #pragma unroll
    for (int i = 0; i < 2; i++)
      af[i] = *(const short8*)&As[wave * 32 + i * 16 + l16][quad * 8];
    #pragma unroll
    for (int j = 0; j < 4; j++)
      bfr[j] = *(const short8*)&Bs[j * 16 + l16][quad * 8];
    #pragma unroll
    for (int i = 0; i < 2; i++)
      #pragma unroll
      for (int j = 0; j < 4; j++)
        acc[i][j] = __builtin_amdgcn_mfma_f32_16x16x32_bf16(af[i], bfr[j], acc[i][j], 0, 0, 0);
    __syncthreads();
  }
  #pragma unroll
  for (int j = 0; j < 4; j++) {
    int nl = n0l + j * 16 + l16;
    float bn = bias[nl];
    float csum = 0.f;
    #pragma unroll
    for (int i = 0; i < 2; i++) {
      #pragma unroll
      for (int r = 0; r < 4; r++) {
        int m = m0 + wave * 32 + i * 16 + quad * 4 + r;
        float v = half ? actf<ACTB>(acc[i][j][r] + bn) : actf<ACTA>(acc[i][j][r] + bn);
        if (KMEAN && half) csum += v;
        Out[(size_t)m * CH + nl] = f2b(v);
      }
    }
    if (KMEAN && half) atomicAdd(&colsum[j * 16 + l16], csum);
  }
  if (KMEAN && half) {
    __syncthreads();
    if (t < 64) {
      int b = m0 >> 12;
      atomicAdd(&KM[b * CH + n0l + t], colsum[t] * (1.f / 4096.f));
    }
  }
}

// ---------------- kv = (1/4096) * sum_n rope(k)[n,d] * v[n,e], per (b,h) ----------------
__global__ __launch_bounds__(256) void k_kv(const bf16* __restrict__ k,
                                            const bf16* __restrict__ v,
                                            const float* __restrict__ cosT,
                                            const float* __restrict__ sinT,
                                            float* __restrict__ kv) {
  int bh = blockIdx.x;
  int b = bh / NHEADS, hd = bh % NHEADS;
  int n0 = blockIdx.y * 128;
  __shared__ float ks[128][36];
  __shared__ float vs[128][36];
  int t = threadIdx.x;
  // phase A: stage bf16 k,v -> fp32 LDS (channel-contiguous loads)
  #pragma unroll
  for (int it = 0; it < 2; it++) {
    int idx = t + it * 256;
    int row = idx >> 2, c0 = (idx & 3) * 8;
    size_t gi = ((size_t)(b * HWSZ + n0 + row)) * CH + hd * HDIM + c0;
    const bf16* kp = k + gi;
    const bf16* vp = v + gi;
    #pragma unroll
    for (int j = 0; j < 8; j++) {
      ks[row][c0 + j] = b2f(kp[j]);
      vs[row][c0 + j] = b2f(vp[j]);
    }
  }
  __syncthreads();
  // phase B: rope in place on ks (row-fastest -> coalesced cos/sin)
  #pragma unroll
  for (int it = 0; it < 8; it++) {
    int pr = it * 2 + (t >> 7);
    int row = t & 127;
    float cs = cosT[(size_t)(hd * 16 + pr) * HWSZ + n0 + row];
    float sn = sinT[(size_t)(hd * 16 + pr) * HWSZ + n0 + row];
    float re = ks[row][2 * pr], im = ks[row][2 * pr + 1];
    ks[row][2 * pr] = re * cs - im * sn;
    ks[row][2 * pr + 1] = re * sn + im * cs;
  }
  __syncthreads();
  // phase C: outer products
  int d = t >> 3;
  int e0 = (t & 7) * 4;
  float a0 = 0, a1 = 0, a2 = 0, a3 = 0;
  for (int i = 0; i < 128; i++) {
    float kd = ks[i][d];
    float4 vv = *(const float4*)&vs[i][e0];
    a0 += kd * vv.x;
    a1 += kd * vv.y;
    a2 += kd * vv.z;
    a3 += kd * vv.w;
  }
  float* dst = kv + (size_t)bh * (HDIM * HDIM) + d * HDIM + e0;
  const float sc = 1.f / 4096.f;
  atomicAdd(dst + 0, a0 * sc);
  atomicAdd(dst + 1, a1 * sc);
  atomicAdd(dst + 2, a2 * sc);
  atomicAdd(dst + 3, a3 * sc);
}

// ---------------- attn: per (pix-chunk, head, batch); kv in LDS ----------------
__global__ __launch_bounds__(256) void k_attn(const bf16* __restrict__ q,
                                              const float* __restrict__ kv,
                                              const float* __restrict__ kmean,
                                              const float* __restrict__ cosT,
                                              const float* __restrict__ sinT,
                                              bf16* __restrict__ attn) {
  int hd = blockIdx.y, b = blockIdx.z;
  int hw = blockIdx.x * 256 + threadIdx.x;
  int bh = b * NHEADS + hd;
  __shared__ float kvs[32][33];
  __shared__ float kms[32];
  #pragma unroll
  for (int i = 0; i < 4; i++) {
    int idx = threadIdx.x + i * 256;
    kvs[idx >> 5][idx & 31] = kv[(size_t)bh * 1024 + idx];
  }
  if (threadIdx.x < 32) kms[threadIdx.x] = kmean[b * CH + hd * HDIM + threadIdx.x];
  __syncthreads();
  int pix = b * HWSZ + hw;
  const bf16* qp = q + (size_t)pix * CH + hd * HDIM;
  float qv[32];
  #pragma unroll
  for (int i = 0; i < 32; i++) qv[i] = b2f(qp[i]);
  float z = 1e-6f;
  #pragma unroll
  for (int d = 0; d < 32; d++) z += qv[d] * kms[d];
  float o[32] = {};
  #pragma unroll
  for (int p = 0; p < 16; p++) {
    float cs = cosT[(size_t)(hd * 16 + p) * HWSZ + hw];
    float sn = sinT[(size_t)(hd * 16 + p) * HWSZ + hw];
    float re = qv[2 * p], im = qv[2 * p + 1];
    float qr = re * cs - im * sn;
    float qi = re * sn + im * cs;
    #pragma unroll
    for (int e = 0; e < 32; e++)
      o[e] += qr * kvs[2 * p][e] + qi * kvs[2 * p + 1][e];
  }
  float zi = 1.f / z;
  bf16* op = attn + (size_t)pix * CH + hd * HDIM;
  #pragma unroll
  for (int i = 0; i < 4; i++) {
    __align__(16) bf16 tmp[8];
    #pragma unroll
    for (int j = 0; j < 8; j++) tmp[j] = f2b(o[i * 8 + j] * zi);
    *(short8*)&op[i * 8] = *(const short8*)tmp;
  }
}

extern "C" void kernel_launch(void* const* d_in, const int* in_sizes, int n_in,
                              void* d_out, int out_size, void* d_ws, size_t ws_size,
                              hipStream_t stream) {
  const float* x = (const float*)d_in[0];
  const float* cpe1w = (const float*)d_in[1];
  const float* cpe1b = (const float*)d_in[2];
  const float* n1w = (const float*)d_in[3];
  const float* n1b = (const float*)d_in[4];
  const float* apw = (const float*)d_in[5];
  const float* apb = (const float*)d_in[6];
  const float* ipw = (const float*)d_in[7];
  const float* ipb = (const float*)d_in[8];
  const float* dwcw = (const float*)d_in[9];
  const float* dwcb = (const float*)d_in[10];
  const float* qkw = (const float*)d_in[11];
  const float* qkb = (const float*)d_in[12];
  const float* lepw = (const float*)d_in[13];
  const float* lepb = (const float*)d_in[14];
  const float* opw = (const float*)d_in[15];
  const float* opb = (const float*)d_in[16];
  const float* cpe2w = (const float*)d_in[17];
  const float* cpe2b = (const float*)d_in[18];
  const float* n2w = (const float*)d_in[19];
  const float* n2b = (const float*)d_in[20];
  const float* f1w = (const float*)d_in[21];
  const float* f1b = (const float*)d_in[22];
  const float* f2w = (const float*)d_in[23];
  const float* f2b = (const float*)d_in[24];
  float* out = (float*)d_out;

  float* ws = (float*)d_ws;
  const size_t S = (size_t)NPIX * CH;  // 12.58M elements
  float* FA = ws;                       // fp32: x NHWC -> (bf16 k/attn scratch) -> x3 -> final
  float* FB = ws + S;                   // fp32: x1 -> (bf16 MLP hidden stripes)
  bf16* barena = (bf16*)(ws + 2 * S);
  bf16* b0 = barena;                    // y -> t/v -> y4
  bf16* b1 = barena + S;                // act_res
  bf16* b2 = barena + 2 * S;            // y2 -> q -> x2
  bf16* KB = (bf16*)FA;                 // k, then attn (FA dead between cpe1 and cpe2)
  float* COS = ws + 2 * S + 3 * S / 2;
  float* SIN = COS + (size_t)NPAIR * HWSZ;
  float* KV = SIN + (size_t)NPAIR * HWSZ;
  float* KM = KV + BQ * NHEADS * HDIM * HDIM;
  bf16* HIDB = (bf16*)FB;               // MLP hidden stripe (NPIX/2 x 768 bf16 = S floats)

  dim3 tb(32, 8);
  // 1. transpose input NCHW -> NHWC fp32
  k_transpose_in<<<dim3(6, 128, BQ), tb, 0, stream>>>(x, FA);
  // 2. rope tables [pair][hw]
  k_rope<<<dim3(NPAIR * HWSZ / 256), dim3(256), 0, stream>>>(COS, SIN);
  // 3. x1 = x + cpe1(x)   (fp32 -> fp32)
  k_dwconv<float, float, 0><<<dim3(BQ * HH), dim3(CH), 0, stream>>>(FA, cpe1w, cpe1b, FB);
  // 4. y = LN1(x1)  (fp32 -> bf16)
  k_ln<<<dim3(NPIX / 4), dim3(256), 0, stream>>>(FB, n1w, n1b, b0);
  // 5. act_res = silu(act_proj(y)); y2 = in_proj(y)   [one A-pass]
  k_gemm_dual<1, 0, 0><<<dim3(NPIX / 128, 6), dim3(256), 0, stream>>>(
      b0, apw, apb, ipw, ipb, b1, b2, nullptr, CH);
  // 6. t = v = silu(dwc(y2))
  k_dwconv<bf16, bf16, 1><<<dim3(BQ * HH), dim3(CH), 0, stream>>>(b2, dwcw, dwcb, b0);
  // 7. q,k = elu(t @ qk_w^T + qk_b)+1 ; kmean fused into k epilogue
  hipMemsetAsync(KM, 0, (size_t)BQ * CH * sizeof(float), stream);
  k_gemm_dual<2, 2, 1><<<dim3(NPIX / 128, 6), dim3(256), 0, stream>>>(
      b0, qkw, qkb, qkw + CH * CH, qkb + CH, b2, KB, KM, CH);
  // 8. kv accumulate
  hipMemsetAsync(KV, 0, (size_t)BQ * NHEADS * HDIM * HDIM * sizeof(float), stream);
  k_kv<<<dim3(BQ * NHEADS, 32), dim3(256), 0, stream>>>(KB, b0, COS, SIN, KV);
  // 9. attn = (q_rope @ kv) * z  -> KB region (k dead)
  k_attn<<<dim3(HWSZ / 256, NHEADS, BQ), dim3(256), 0, stream>>>(b2, KV, KM, COS, SIN, KB);
  // 10. attn += lepe(v)
  k_dwconv<bf16, bf16, 2><<<dim3(BQ * HH), dim3(CH), 0, stream>>>(b0, lepw, lepb, KB);
  // 11. x2 = x1 + out_proj(attn * act_res)  -> b2 (bf16)
  k_gemm<0, 1, 1, bf16><<<dim3(NPIX / 128, 3), dim3(256), 0, stream>>>(
      KB, b1, opw, opb, FB, b2, NPIX, CH, CH);
  // 12. x3 = x2 + cpe2(x2)  (bf16 -> fp32, overwrites FA)
  k_dwconv<bf16, float, 0><<<dim3(BQ * HH), dim3(CH), 0, stream>>>(b2, cpe2w, cpe2b, FA);
  // 13. y4 = LN2(x3)  (fp32 -> bf16)
  k_ln<<<dim3(NPIX / 4), dim3(256), 0, stream>>>(FA, n2w, n2b, b0);
  // 14. MLP in 2 stripes; hidden bf16 stripe lives in FB (x1 dead)
  for (int s = 0; s < 2; s++) {
    size_t offb = (size_t)s * (NPIX / 2) * CH;   // bf16 elements
    size_t offf = (size_t)s * (NPIX / 2) * CH;   // fp32 elements (same count)
    k_gemm<3, 0, 0, bf16><<<dim3((NPIX / 2) / 128, HID / 64), dim3(256), 0, stream>>>(
        b0 + offb, (const bf16*)nullptr, f1w, f1b, (const float*)nullptr, HIDB, NPIX / 2, HID, CH);
    k_gemm<0, 0, 1, float><<<dim3((NPIX / 2) / 128, 3), dim3(256), 0, stream>>>(
        HIDB, (const bf16*)nullptr, f2w, f2b, FA + offf, FA + offf, NPIX / 2, CH, HID);
  }
  // 15. final transpose NHWC fp32 -> NCHW fp32
  k_transpose_out<<<dim3(6, 128, BQ), tb, 0, stream>>>(FA, out);
}

// Round 5
// 726.274 us; speedup vs baseline: 3.0232x; 1.0981x over previous
//
#include <hip/hip_runtime.h>
#include <hip/hip_bf16.h>

#define BQ 16
#define CH 192
#define HH 64
#define WW 64
#define HWSZ 4096
#define NPIX 65536
#define NHEADS 6
#define HDIM 32
#define NPAIR 96
#define KMAXR 48
#define HID 768

typedef __hip_bfloat16 bf16;
typedef __attribute__((ext_vector_type(8))) short short8;
typedef __attribute__((ext_vector_type(4))) float floatx4;

static __device__ __forceinline__ float b2f(bf16 v) { return __bfloat162float(v); }
static __device__ __forceinline__ bf16 f2b(float v) { return __float2bfloat16(v); }

static __device__ __forceinline__ float4 ld4(const float* p) { return *(const float4*)p; }
static __device__ __forceinline__ float4 ld4(const bf16* p) {
  uint2 u = *(const uint2*)p;
  return make_float4(__uint_as_float(u.x << 16), __uint_as_float(u.x & 0xffff0000u),
                     __uint_as_float(u.y << 16), __uint_as_float(u.y & 0xffff0000u));
}

template <int ACT>
static __device__ __forceinline__ float actf(float v) {
  if (ACT == 1) return v / (1.f + expf(-v));                               // silu
  if (ACT == 2) return (v > 0.f) ? v + 1.f : expf(v);                      // elu+1
  if (ACT == 3) return 0.5f * v * (1.f + erff(v * 0.70710678118654752f));  // gelu
  return v;
}
static __device__ __forceinline__ void stv(float* p, float v) { *p = v; }
static __device__ __forceinline__ void stv(bf16* p, float v) { *p = __float2bfloat16(v); }

// ---------------- transpose NCHW -> NHWC (fp32) ----------------
__global__ __launch_bounds__(256) void k_transpose_in(const float* __restrict__ in,
                                                      float* __restrict__ out) {
  __shared__ float tile[32][33];
  int c0 = blockIdx.x * 32, hw0 = blockIdx.y * 32, b = blockIdx.z;
  int tx = threadIdx.x, ty = threadIdx.y;
  const float* src = in + (size_t)b * CH * HWSZ;
  #pragma unroll
  for (int j = 0; j < 32; j += 8)
    tile[ty + j][tx] = src[(size_t)(c0 + ty + j) * HWSZ + hw0 + tx];
  __syncthreads();
  float* dst = out + (size_t)b * HWSZ * CH;
  #pragma unroll
  for (int j = 0; j < 32; j += 8)
    dst[(size_t)(hw0 + ty + j) * CH + c0 + tx] = tile[tx][ty + j];
}

// ---------------- transpose NHWC -> NCHW (fp32) ----------------
__global__ __launch_bounds__(256) void k_transpose_out(const float* __restrict__ in,
                                                       float* __restrict__ out) {
  __shared__ float tile[32][33];
  int c0 = blockIdx.x * 32, hw0 = blockIdx.y * 32, b = blockIdx.z;
  int tx = threadIdx.x, ty = threadIdx.y;
  const float* src = in + (size_t)b * HWSZ * CH;
  #pragma unroll
  for (int j = 0; j < 32; j += 8)
    tile[ty + j][tx] = src[(size_t)(hw0 + ty + j) * CH + c0 + tx];
  __syncthreads();
  float* dst = out + (size_t)b * CH * HWSZ;
  #pragma unroll
  for (int j = 0; j < 32; j += 8)
    dst[(size_t)(c0 + ty + j) * HWSZ + hw0 + tx] = tile[tx][ty + j];
}

// ---------------- RoPE tables, layout [pair][hw] ----------------
__global__ __launch_bounds__(256) void k_rope(float* __restrict__ cosT, float* __restrict__ sinT) {
  int i = blockIdx.x * 256 + threadIdx.x;
  if (i >= NPAIR * HWSZ) return;
  int hw = i & (HWSZ - 1);
  int p = i >> 12;
  int h = hw >> 6, w = hw & 63;
  int j = (p < KMAXR) ? p : p - KMAXR;
  float theta = powf(10000.f, -(float)j / (float)KMAXR);
  float pos = (p < KMAXR) ? (float)h : (float)w;
  float ang = pos * theta;
  cosT[i] = cosf(ang);
  sinT[i] = sinf(ang);
}

// ---------------- fused dwconv(residual) + LayerNorm ----------------
// block = 4 pixels x 48 channel-groups (4ch each), 192 threads.
// x1 = in + conv(in)+bias  (fp32 out); y = LN(x1)*g+bt (bf16 out)
template <typename TI>
__global__ __launch_bounds__(192) void k_cpe_ln(const TI* __restrict__ in,
                                                const float* __restrict__ w,
                                                const float* __restrict__ bias,
                                                const float* __restrict__ g,
                                                const float* __restrict__ bt,
                                                float* __restrict__ x1o,
                                                bf16* __restrict__ yo) {
  __shared__ float sred[192], ssred[192];
  int t = threadIdx.x;
  int cg = t % 48, pl = t / 48;
  int pix = blockIdx.x * 4 + pl;
  int hw = pix & (HWSZ - 1);
  int h = hw >> 6, wx = hw & 63;
  int c0 = cg * 4;
  // per-thread weights: 36 contiguous floats (4 channels x 9 taps)
  float4 w4[9];
  #pragma unroll
  for (int i = 0; i < 9; i++) w4[i] = ld4(w + c0 * 9 + i * 4);
  float4 bi = ld4(bias + c0);
  float acc0 = bi.x, acc1 = bi.y, acc2 = bi.z, acc3 = bi.w;
  float4 ctr;
  const TI* base = in + (size_t)pix * CH + c0;
  #pragma unroll
  for (int dh = -1; dh <= 1; dh++) {
    #pragma unroll
    for (int dw = -1; dw <= 1; dw++) {
      bool v = ((unsigned)(h + dh) < HH) && ((unsigned)(wx + dw) < WW);
      float4 tv = v ? ld4(base + (dh * WW + dw) * CH) : make_float4(0, 0, 0, 0);
      if (dh == 0 && dw == 0) ctr = tv;
      const int tap = (dh + 1) * 3 + (dw + 1);
      // weight for channel j, tap: flat index j*9+tap of w4[]
      #define WX(j) (((const float*)w4)[(j) * 9 + tap])
      acc0 += tv.x * WX(0);
      acc1 += tv.y * WX(1);
      acc2 += tv.z * WX(2);
      acc3 += tv.w * WX(3);
      #undef WX
    }
  }
  float x0 = ctr.x + acc0, x1 = ctr.y + acc1, x2 = ctr.z + acc2, x3 = ctr.w + acc3;
  *(float4*)&x1o[(size_t)pix * CH + c0] = make_float4(x0, x1, x2, x3);
  sred[t] = x0 + x1 + x2 + x3;
  ssred[t] = x0 * x0 + x1 * x1 + x2 * x2 + x3 * x3;
  __syncthreads();
  float S = 0.f, SS = 0.f;
  int rb = pl * 48;
  #pragma unroll
  for (int i = 0; i < 48; i++) { S += sred[rb + i]; SS += ssred[rb + i]; }
  float mu = S * (1.f / CH);
  float inv = rsqrtf(SS * (1.f / CH) - mu * mu + 1e-5f);
  float4 gg = ld4(g + c0);
  float4 bb = ld4(bt + c0);
  __align__(8) bf16 tmp[4] = {f2b((x0 - mu) * inv * gg.x + bb.x),
                              f2b((x1 - mu) * inv * gg.y + bb.y),
                              f2b((x2 - mu) * inv * gg.z + bb.z),
                              f2b((x3 - mu) * inv * gg.w + bb.w)};
  *(uint2*)&yo[(size_t)pix * CH + c0] = *(uint2*)tmp;
}

// ---------------- vectorized dwconv, bf16 in/out, 4ch per thread ----------------
// MODE 1: out = silu(conv+bias)   MODE 2: out += conv+bias
template <int MODE>
__global__ __launch_bounds__(256) void k_dwconv4(const bf16* __restrict__ in,
                                                 const float* __restrict__ w,
                                                 const float* __restrict__ bias,
                                                 bf16* __restrict__ out) {
  int id = blockIdx.x * 256 + threadIdx.x;  // NPIX*48
  int cg = id % 48, pix = id / 48;
  int hw = pix & (HWSZ - 1);
  int h = hw >> 6, wx = hw & 63;
  int c0 = cg * 4;
  float4 w4[9];
  #pragma unroll
  for (int i = 0; i < 9; i++) w4[i] = ld4(w + c0 * 9 + i * 4);
  float4 bi = ld4(bias + c0);
  float acc0 = bi.x, acc1 = bi.y, acc2 = bi.z, acc3 = bi.w;
  const bf16* base = in + (size_t)pix * CH + c0;
  #pragma unroll
  for (int dh = -1; dh <= 1; dh++) {
    #pragma unroll
    for (int dw = -1; dw <= 1; dw++) {
      bool v = ((unsigned)(h + dh) < HH) && ((unsigned)(wx + dw) < WW);
      float4 tv = v ? ld4(base + (dh * WW + dw) * CH) : make_float4(0, 0, 0, 0);
      const int tap = (dh + 1) * 3 + (dw + 1);
      #define WX(j) (((const float*)w4)[(j) * 9 + tap])
      acc0 += tv.x * WX(0);
      acc1 += tv.y * WX(1);
      acc2 += tv.z * WX(2);
      acc3 += tv.w * WX(3);
      #undef WX
    }
  }
  bf16* op = out + (size_t)pix * CH + c0;
  if (MODE == 1) {
    acc0 = acc0 / (1.f + expf(-acc0));
    acc1 = acc1 / (1.f + expf(-acc1));
    acc2 = acc2 / (1.f + expf(-acc2));
    acc3 = acc3 / (1.f + expf(-acc3));
  } else {
    float4 cur = ld4(op);
    acc0 += cur.x; acc1 += cur.y; acc2 += cur.z; acc3 += cur.w;
  }
  __align__(8) bf16 tmp[4] = {f2b(acc0), f2b(acc1), f2b(acc2), f2b(acc3)};
  *(uint2*)op = *(uint2*)tmp;
}

// ---------------- MFMA bf16 GEMM: tile 128x64, BK=32 ----------------
template <int ACT, int MULA, int RES, typename TO>
__global__ __launch_bounds__(256) void k_gemm(const bf16* __restrict__ A,
                                              const bf16* __restrict__ A2,
                                              const float* __restrict__ Wt,
                                              const float* __restrict__ bias,
                                              const float* __restrict__ Rsd,
                                              TO* __restrict__ Cout,
                                              int M, int N, int K) {
  __shared__ bf16 As[128][40];
  __shared__ bf16 Bs[64][40];
  int t = threadIdx.x;
  int wave = t >> 6, lane = t & 63;
  int quad = lane >> 4, l16 = lane & 15;
  int m0 = blockIdx.x * 128, n0 = blockIdx.y * 64;
  floatx4 acc[2][4] = {};
  for (int k0 = 0; k0 < K; k0 += 32) {
    #pragma unroll
    for (int i = 0; i < 2; i++) {
      int idx = t + i * 256;
      int m = idx >> 2, kk = (idx & 3) * 8;
      const bf16* pa = &A[(size_t)(m0 + m) * K + k0 + kk];
      if (!MULA) {
        *(short8*)&As[m][kk] = *(const short8*)pa;
      } else {
        const bf16* pb = &A2[(size_t)(m0 + m) * K + k0 + kk];
        __align__(16) bf16 tmp[8];
        #pragma unroll
        for (int j = 0; j < 8; j++) tmp[j] = f2b(b2f(pa[j]) * b2f(pb[j]));
        *(short8*)&As[m][kk] = *(const short8*)tmp;
      }
    }
    #pragma unroll
    for (int i = 0; i < 2; i++) {
      int idx = t + i * 256;
      int n = idx >> 3, kk = (idx & 7) * 4;
      float4 v = *(const float4*)&Wt[(size_t)(n0 + n) * K + k0 + kk];
      __align__(8) bf16 tmp[4] = {f2b(v.x), f2b(v.y), f2b(v.z), f2b(v.w)};
      *(uint2*)&Bs[n][kk] = *(uint2*)tmp;
    }
    __syncthreads();
    short8 af[2], bfr[4];
    #pragma unroll
    for (int i = 0; i < 2; i++)
      af[i] = *(const short8*)&As[wave * 32 + i * 16 + l16][quad * 8];
    #pragma unroll
    for (int j = 0; j < 4; j++)
      bfr[j] = *(const short8*)&Bs[j * 16 + l16][quad * 8];
    #pragma unroll
    for (int i = 0; i < 2; i++)
      #pragma unroll
      for (int j = 0; j < 4; j++)
        acc[i][j] = __builtin_amdgcn_mfma_f32_16x16x32_bf16(af[i], bfr[j], acc[i][j], 0, 0, 0);
    __syncthreads();
  }
  #pragma unroll
  for (int i = 0; i < 2; i++) {
    #pragma unroll
    for (int j = 0; j < 4; j++) {
      int n = n0 + j * 16 + l16;
      float bn = bias[n];
      #pragma unroll
      for (int r = 0; r < 4; r++) {
        int m = m0 + wave * 32 + i * 16 + quad * 4 + r;
        float v = actf<ACT>(acc[i][j][r] + bn);
        if (RES) v += Rsd[(size_t)m * N + n];
        stv(&Cout[(size_t)m * N + n], v);
      }
    }
  }
}

// dual-output GEMM: N=384 as two 192 halves; optional fused column-mean of half B.
template <int ACTA, int ACTB, int KMEAN>
__global__ __launch_bounds__(256) void k_gemm_dual(const bf16* __restrict__ A,
                                                   const float* __restrict__ WtA,
                                                   const float* __restrict__ biasA,
                                                   const float* __restrict__ WtB,
                                                   const float* __restrict__ biasB,
                                                   bf16* __restrict__ OutA,
                                                   bf16* __restrict__ OutB,
                                                   float* __restrict__ KM,
                                                   int K) {
  __shared__ bf16 As[128][40];
  __shared__ bf16 Bs[64][40];
  __shared__ float colsum[64];
  int t = threadIdx.x;
  int wave = t >> 6, lane = t & 63;
  int quad = lane >> 4, l16 = lane & 15;
  int m0 = blockIdx.x * 128, n0 = blockIdx.y * 64;
  int half = n0 >= 192;
  int n0l = half ? n0 - 192 : n0;
  const float* Wt = half ? WtB : WtA;
  const float* bias = half ? biasB : biasA;
  bf16* Out = half ? OutB : OutA;
  if (KMEAN && half && t < 64) colsum[t] = 0.f;
  floatx4 acc[2][4] = {};
  for (int k0 = 0; k0 < K; k0 += 32) {
    #pragma unroll
    for (int i = 0; i < 2; i++) {
      int idx = t + i * 256;
      int m = idx >> 2, kk = (idx & 3) * 8;
      *(short8*)&As[m][kk] = *(const short8*)&A[(size_t)(m0 + m) * K + k0 + kk];
    }
    #pragma unroll
    for (int i = 0; i < 2; i++) {
      int idx = t + i * 256;
      int n = idx >> 3, kk = (idx & 7) * 4;
      float4 v = *(const float4*)&Wt[(size_t)(n0l + n) * K + k0 + kk];
      __align__(8) bf16 tmp[4] = {f2b(v.x), f2b(v.y), f2b(v.z), f2b(v.w)};
      *(uint2*)&Bs[n][kk] = *(uint2*)tmp;
    }
    __syncthreads();
    short8 af[2], bfr[4];
    #pragma unroll
    for (int i = 0; i < 2; i++)
      af[i] = *(const short8*)&As[wave * 32 + i * 16 + l16][quad * 8];
    #pragma unroll
    for (int j = 0; j < 4; j++)
      bfr[j] = *(const short8*)&Bs[j * 16 + l16][quad * 8];
    #pragma unroll
    for (int i = 0; i < 2; i++)
      #pragma unroll
      for (int j = 0; j < 4; j++)
        acc[i][j] = __builtin_amdgcn_mfma_f32_16x16x32_bf16(af[i], bfr[j], acc[i][j], 0, 0, 0);
    __syncthreads();
  }
  #pragma unroll
  for (int j = 0; j < 4; j++) {
    int nl = n0l + j * 16 + l16;
    float bn = bias[nl];
    float csum = 0.f;
    #pragma unroll
    for (int i = 0; i < 2; i++) {
      #pragma unroll
      for (int r = 0; r < 4; r++) {
        int m = m0 + wave * 32 + i * 16 + quad * 4 + r;
        float v = half ? actf<ACTB>(acc[i][j][r] + bn) : actf<ACTA>(acc[i][j][r] + bn);
        if (KMEAN && half) csum += v;
        Out[(size_t)m * CH + nl] = f2b(v);
      }
    }
    if (KMEAN && half) atomicAdd(&colsum[j * 16 + l16], csum);
  }
  if (KMEAN && half) {
    __syncthreads();
    if (t < 64) {
      int b = m0 >> 12;
      atomicAdd(&KM[b * CH + n0l + t], colsum[t] * (1.f / 4096.f));
    }
  }
}

// ---------------- kv = (1/4096) * sum_n rope(k)[n,d] * v[n,e], per (b,h) ----------------
__global__ __launch_bounds__(256) void k_kv(const bf16* __restrict__ k,
                                            const bf16* __restrict__ v,
                                            const float* __restrict__ cosT,
                                            const float* __restrict__ sinT,
                                            float* __restrict__ kv) {
  int bh = blockIdx.x;
  int b = bh / NHEADS, hd = bh % NHEADS;
  int n0 = blockIdx.y * 128;
  __shared__ float ks[128][36];
  __shared__ float vs[128][36];
  int t = threadIdx.x;
  #pragma unroll
  for (int it = 0; it < 2; it++) {
    int idx = t + it * 256;
    int row = idx >> 2, c0 = (idx & 3) * 8;
    size_t gi = ((size_t)(b * HWSZ + n0 + row)) * CH + hd * HDIM + c0;
    const bf16* kp = k + gi;
    const bf16* vp = v + gi;
    #pragma unroll
    for (int j = 0; j < 8; j++) {
      ks[row][c0 + j] = b2f(kp[j]);
      vs[row][c0 + j] = b2f(vp[j]);
    }
  }
  __syncthreads();
  #pragma unroll
  for (int it = 0; it < 8; it++) {
    int pr = it * 2 + (t >> 7);
    int row = t & 127;
    float cs = cosT[(size_t)(hd * 16 + pr) * HWSZ + n0 + row];
    float sn = sinT[(size_t)(hd * 16 + pr) * HWSZ + n0 + row];
    float re = ks[row][2 * pr], im = ks[row][2 * pr + 1];
    ks[row][2 * pr] = re * cs - im * sn;
    ks[row][2 * pr + 1] = re * sn + im * cs;
  }
  __syncthreads();
  int d = t >> 3;
  int e0 = (t & 7) * 4;
  float a0 = 0, a1 = 0, a2 = 0, a3 = 0;
  for (int i = 0; i < 128; i++) {
    float kd = ks[i][d];
    float4 vv = *(const float4*)&vs[i][e0];
    a0 += kd * vv.x;
    a1 += kd * vv.y;
    a2 += kd * vv.z;
    a3 += kd * vv.w;
  }
  float* dst = kv + (size_t)bh * (HDIM * HDIM) + d * HDIM + e0;
  const float sc = 1.f / 4096.f;
  atomicAdd(dst + 0, a0 * sc);
  atomicAdd(dst + 1, a1 * sc);
  atomicAdd(dst + 2, a2 * sc);
  atomicAdd(dst + 3, a3 * sc);
}

// ---------------- attn: per (pix-chunk, head, batch); kv in LDS ----------------
__global__ __launch_bounds__(256) void k_attn(const bf16* __restrict__ q,
                                              const float* __restrict__ kv,
                                              const float* __restrict__ kmean,
                                              const float* __restrict__ cosT,
                                              const float* __restrict__ sinT,
                                              bf16* __restrict__ attn) {
  int hd = blockIdx.y, b = blockIdx.z;
  int hw = blockIdx.x * 256 + threadIdx.x;
  int bh = b * NHEADS + hd;
  __shared__ float kvs[32][33];
  __shared__ float kms[32];
  #pragma unroll
  for (int i = 0; i < 4; i++) {
    int idx = threadIdx.x + i * 256;
    kvs[idx >> 5][idx & 31] = kv[(size_t)bh * 1024 + idx];
  }
  if (threadIdx.x < 32) kms[threadIdx.x] = kmean[b * CH + hd * HDIM + threadIdx.x];
  __syncthreads();
  int pix = b * HWSZ + hw;
  const bf16* qp = q + (size_t)pix * CH + hd * HDIM;
  float qv[32];
  #pragma unroll
  for (int i = 0; i < 32; i++) qv[i] = b2f(qp[i]);
  float z = 1e-6f;
  #pragma unroll
  for (int d = 0; d < 32; d++) z += qv[d] * kms[d];
  float o[32] = {};
  #pragma unroll
  for (int p = 0; p < 16; p++) {
    float cs = cosT[(size_t)(hd * 16 + p) * HWSZ + hw];
    float sn = sinT[(size_t)(hd * 16 + p) * HWSZ + hw];
    float re = qv[2 * p], im = qv[2 * p + 1];
    float qr = re * cs - im * sn;
    float qi = re * sn + im * cs;
    #pragma unroll
    for (int e = 0; e < 32; e++)
      o[e] += qr * kvs[2 * p][e] + qi * kvs[2 * p + 1][e];
  }
  float zi = 1.f / z;
  bf16* op = attn + (size_t)pix * CH + hd * HDIM;
  #pragma unroll
  for (int i = 0; i < 4; i++) {
    __align__(16) bf16 tmp[8];
    #pragma unroll
    for (int j = 0; j < 8; j++) tmp[j] = f2b(o[i * 8 + j] * zi);
    *(short8*)&op[i * 8] = *(const short8*)tmp;
  }
}

extern "C" void kernel_launch(void* const* d_in, const int* in_sizes, int n_in,
                              void* d_out, int out_size, void* d_ws, size_t ws_size,
                              hipStream_t stream) {
  const float* x = (const float*)d_in[0];
  const float* cpe1w = (const float*)d_in[1];
  const float* cpe1b = (const float*)d_in[2];
  const float* n1w = (const float*)d_in[3];
  const float* n1b = (const float*)d_in[4];
  const float* apw = (const float*)d_in[5];
  const float* apb = (const float*)d_in[6];
  const float* ipw = (const float*)d_in[7];
  const float* ipb = (const float*)d_in[8];
  const float* dwcw = (const float*)d_in[9];
  const float* dwcb = (const float*)d_in[10];
  const float* qkw = (const float*)d_in[11];
  const float* qkb = (const float*)d_in[12];
  const float* lepw = (const float*)d_in[13];
  const float* lepb = (const float*)d_in[14];
  const float* opw = (const float*)d_in[15];
  const float* opb = (const float*)d_in[16];
  const float* cpe2w = (const float*)d_in[17];
  const float* cpe2b = (const float*)d_in[18];
  const float* n2w = (const float*)d_in[19];
  const float* n2b = (const float*)d_in[20];
  const float* f1w = (const float*)d_in[21];
  const float* f1b = (const float*)d_in[22];
  const float* f2w = (const float*)d_in[23];
  const float* f2b = (const float*)d_in[24];
  float* out = (float*)d_out;

  float* ws = (float*)d_ws;
  const size_t S = (size_t)NPIX * CH;
  float* FA = ws;                       // fp32: x NHWC -> (bf16 k/attn scratch) -> x3 -> final
  float* FB = ws + S;                   // fp32: x1 -> (bf16 MLP hidden stripes)
  bf16* barena = (bf16*)(ws + 2 * S);
  bf16* b0 = barena;                    // y -> t/v -> y4
  bf16* b1 = barena + S;                // act_res
  bf16* b2 = barena + 2 * S;            // y2 -> q -> x2
  bf16* KB = (bf16*)FA;                 // k, then attn (FA dead between cpe1 and cpe2)
  float* COS = ws + 2 * S + 3 * S / 2;
  float* SIN = COS + (size_t)NPAIR * HWSZ;
  float* KV = SIN + (size_t)NPAIR * HWSZ;
  float* KM = KV + BQ * NHEADS * HDIM * HDIM;
  bf16* HIDB = (bf16*)FB;

  dim3 tb(32, 8);
  // 1. transpose input NCHW -> NHWC fp32
  k_transpose_in<<<dim3(6, 128, BQ), tb, 0, stream>>>(x, FA);
  // 2. rope tables [pair][hw]
  k_rope<<<dim3(NPAIR * HWSZ / 256), dim3(256), 0, stream>>>(COS, SIN);
  // 3. x1 = x + cpe1(x); y = LN1(x1)   [fused]
  k_cpe_ln<float><<<dim3(NPIX / 4), dim3(192), 0, stream>>>(FA, cpe1w, cpe1b, n1w, n1b, FB, b0);
  // 4. act_res = silu(act_proj(y)); y2 = in_proj(y)
  k_gemm_dual<1, 0, 0><<<dim3(NPIX / 128, 6), dim3(256), 0, stream>>>(
      b0, apw, apb, ipw, ipb, b1, b2, nullptr, CH);
  // 5. t = v = silu(dwc(y2))
  k_dwconv4<1><<<dim3(NPIX * 48 / 256), dim3(256), 0, stream>>>(b2, dwcw, dwcb, b0);
  // 6. q,k = elu(t @ qk_w^T + qk_b)+1 ; kmean fused into k epilogue
  hipMemsetAsync(KM, 0, (size_t)BQ * CH * sizeof(float), stream);
  k_gemm_dual<2, 2, 1><<<dim3(NPIX / 128, 6), dim3(256), 0, stream>>>(
      b0, qkw, qkb, qkw + CH * CH, qkb + CH, b2, KB, KM, CH);
  // 7. kv accumulate
  hipMemsetAsync(KV, 0, (size_t)BQ * NHEADS * HDIM * HDIM * sizeof(float), stream);
  k_kv<<<dim3(BQ * NHEADS, 32), dim3(256), 0, stream>>>(KB, b0, COS, SIN, KV);
  // 8. attn = (q_rope @ kv) * z  -> KB (k dead)
  k_attn<<<dim3(HWSZ / 256, NHEADS, BQ), dim3(256), 0, stream>>>(b2, KV, KM, COS, SIN, KB);
  // 9. attn += lepe(v)
  k_dwconv4<2><<<dim3(NPIX * 48 / 256), dim3(256), 0, stream>>>(b0, lepw, lepb, KB);
  // 10. x2 = x1 + out_proj(attn * act_res)  -> b2 (bf16)
  k_gemm<0, 1, 1, bf16><<<dim3(NPIX / 128, 3), dim3(256), 0, stream>>>(
      KB, b1, opw, opb, FB, b2, NPIX, CH, CH);
  // 11. x3 = x2 + cpe2(x2); y4 = LN2(x3)   [fused]
  k_cpe_ln<bf16><<<dim3(NPIX / 4), dim3(192), 0, stream>>>(b2, cpe2w, cpe2b, n2w, n2b, FA, b0);
  // 12. MLP in 2 stripes; hidden bf16 stripe lives in FB (x1 dead)
  for (int s = 0; s < 2; s++) {
    size_t off = (size_t)s * (NPIX / 2) * CH;
    k_gemm<3, 0, 0, bf16><<<dim3((NPIX / 2) / 128, HID / 64), dim3(256), 0, stream>>>(
        b0 + off, (const bf16*)nullptr, f1w, f1b, (const float*)nullptr, HIDB, NPIX / 2, HID, CH);
    k_gemm<0, 0, 1, float><<<dim3((NPIX / 2) / 128, 3), dim3(256), 0, stream>>>(
        HIDB, (const bf16*)nullptr, f2w, f2b, FA + off, FA + off, NPIX / 2, CH, HID);
  }
  // 13. final transpose NHWC fp32 -> NCHW fp32
  k_transpose_out<<<dim3(6, 128, BQ), tb, 0, stream>>>(FA, out);
}